// Round 21
// baseline (417.727 us; speedup 1.0000x reference)
//
#include <hip/hip_runtime.h>
#include <cmath>

#define LSEQ 32
#define HID  512
#define DIN  1536
#define CCH  64
#define NROW 2048          // E*S
#define NL   65536         // NROW*LSEQ

typedef _Float16 f16;
typedef _Float16 f16x8 __attribute__((ext_vector_type(8)));
typedef float    f32x4 __attribute__((ext_vector_type(4)));
typedef int      i32x4 __attribute__((ext_vector_type(4)));
typedef unsigned long long u64;

__device__ __forceinline__ float fast_tanh(float x) {
  float e = __expf(2.0f * x);
  return 1.0f - 2.0f * __builtin_amdgcn_rcpf(e + 1.0f);
}

// 64B-row LDS tile, 16B-granularity XOR swizzle
__device__ __forceinline__ int offA(int r, int b) {
  return (r << 6) + (b ^ (((r >> 1) & 3) << 4));
}
// 1KB-row LDS tile
__device__ __forceinline__ int offB(int r, int b) {
  return (r << 10) + (b ^ ((r & 7) << 4));
}

// ---------------- pack conv weights transposed: Wc_t[dl+3][c][k] f16 ----------------
__global__ void pack_wc_kernel(const float* __restrict__ w1, const float* __restrict__ w3,
                               const float* __restrict__ w5, const float* __restrict__ w7,
                               f16* __restrict__ Wc_t) {
  int idx = blockIdx.x * 256 + threadIdx.x;
  if (idx >= 7 * 512 * 512) return;
  int k   = idx & 511;
  int c   = (idx >> 9) & 511;
  int dli = idx >> 18;
  int dl  = dli - 3;
  int g   = c >> 7, cg = c & 127;
  int K   = 2 * g + 1;
  int kk  = dl + g;
  float v = 0.f;
  if (kk >= 0 && kk < K) {
    const float* w = (g == 0) ? w1 : (g == 1) ? w3 : (g == 2) ? w5 : w7;
    v = w[(cg * 512 + k) * K + kk];
  }
  Wc_t[idx] = (f16)v;
}

// ---------------- pack Wh^T, Wout^T, Wx^T as f16 ----------------
__global__ void pack_misc_kernel(const float* __restrict__ Wh, const float* __restrict__ Wout,
                                 const float* __restrict__ Wx,
                                 f16* __restrict__ Wh_t, f16* __restrict__ Wout_t,
                                 f16* __restrict__ Wx_t) {
  int idx = blockIdx.x * 256 + threadIdx.x;
  if (idx < 512 * 512) {
    int n = idx >> 9, k = idx & 511;
    Wh_t[idx] = (f16)Wh[k * 512 + n];
  } else if (idx < 512 * 512 + 64 * 512) {
    int j = idx - 512 * 512;
    int c = j >> 9, k = j & 511;
    Wout_t[j] = (f16)Wout[k * 64 + c];
  } else {
    int j = idx - (512 * 512 + 64 * 512);
    if (j < 512 * 1536) {
      int n = j / 1536, k = j - n * 1536;
      Wx_t[j] = (f16)Wx[k * 512 + n];
    }
  }
}

// ---------------- xw = x @ Wx + bx via f16 MFMA; x converted to hi/lo ON THE FLY ----------------
__global__ __launch_bounds__(256) void xw_mfma_kernel(
    const float* __restrict__ x, const f16* __restrict__ Wx_t,
    const float* __restrict__ bx, float* __restrict__ xw)
{
  __shared__ __align__(16) char Ah[2][4096], Al[2][4096], Bt[2][8192];
  const int tid = threadIdx.x, lane = tid & 63, wave = tid >> 6;
  const int r0 = blockIdx.x * 64, c0 = blockIdx.y * 128;
  const int wr = (wave >> 1) * 32, wc = (wave & 1) * 64;
  const int q = lane >> 4, ln = lane & 15, qb = q << 4;

  const int arow = tid & 63, acb = (tid >> 6) << 4;   // 16B f16 chunk per thread
  const char* srcX = (const char*)(x + (size_t)(r0 + arow) * DIN) + (acb << 1);  // 32B f32
  const int wAo = offA(arow, acb);
  const int brow = tid & 127, bcb = (tid >> 7) << 5;
  const char* srcB = (const char*)(Wx_t + (size_t)(c0 + brow) * DIN) + bcb;
  const int wB0 = offA(brow, bcb), wB1 = offA(brow, bcb + 16);

  {
    float4 xa = *(const float4*)(srcX);
    float4 xb = *(const float4*)(srcX + 16);
    const float f[8] = {xa.x, xa.y, xa.z, xa.w, xb.x, xb.y, xb.z, xb.w};
    union { int4 i; f16 h[8]; } Hi, Lo;
#pragma unroll
    for (int j = 0; j < 8; ++j) {
      f16 hi = (f16)f[j];
      Hi.h[j] = hi;
      Lo.h[j] = (f16)(f[j] - (float)hi);
    }
    *(int4*)(Ah[0] + wAo) = Hi.i;
    *(int4*)(Al[0] + wAo) = Lo.i;
  }
  *(int4*)(Bt[0] + wB0) = *(const int4*)(srcB);
  *(int4*)(Bt[0] + wB1) = *(const int4*)(srcB + 16);
  __syncthreads();

  f32x4 acc[2][4] = {};
  for (int kk = 0; kk < 48; ++kk) {
    const int buf = kk & 1;
    float4 xa, xb;
    int4 rb0, rb1;
    if (kk < 47) {
      xa  = *(const float4*)(srcX + (kk + 1) * 128);
      xb  = *(const float4*)(srcX + (kk + 1) * 128 + 16);
      rb0 = *(const int4*)(srcB + (kk + 1) * 64);
      rb1 = *(const int4*)(srcB + (kk + 1) * 64 + 16);
    }
    f16x8 bf[4];
#pragma unroll
    for (int n = 0; n < 4; ++n)
      bf[n] = *(const f16x8*)(Bt[buf] + offA(wc + n * 16 + ln, qb));
#pragma unroll
    for (int m = 0; m < 2; ++m) {
      f16x8 ah = *(const f16x8*)(Ah[buf] + offA(wr + m * 16 + ln, qb));
      f16x8 al = *(const f16x8*)(Al[buf] + offA(wr + m * 16 + ln, qb));
#pragma unroll
      for (int n = 0; n < 4; ++n) {
        acc[m][n] = __builtin_amdgcn_mfma_f32_16x16x32_f16(ah, bf[n], acc[m][n], 0, 0, 0);
        acc[m][n] = __builtin_amdgcn_mfma_f32_16x16x32_f16(al, bf[n], acc[m][n], 0, 0, 0);
      }
    }
    if (kk < 47) {
      const float f[8] = {xa.x, xa.y, xa.z, xa.w, xb.x, xb.y, xb.z, xb.w};
      union { int4 i; f16 h[8]; } Hi, Lo;
#pragma unroll
      for (int j = 0; j < 8; ++j) {
        f16 hi = (f16)f[j];
        Hi.h[j] = hi;
        Lo.h[j] = (f16)(f[j] - (float)hi);
      }
      *(int4*)(Ah[buf ^ 1] + wAo) = Hi.i;
      *(int4*)(Al[buf ^ 1] + wAo) = Lo.i;
      *(int4*)(Bt[buf ^ 1] + wB0) = rb0;
      *(int4*)(Bt[buf ^ 1] + wB1) = rb1;
      __syncthreads();
    }
  }
#pragma unroll
  for (int m = 0; m < 2; ++m)
#pragma unroll
    for (int i = 0; i < 4; ++i) {
      const int R = r0 + wr + m * 16 + q * 4 + i;
#pragma unroll
      for (int n = 0; n < 4; ++n) {
        const int C = c0 + wc + n * 16 + ln;
        xw[(size_t)R * HID + C] = acc[m][n][i] + bx[C];
      }
    }
}

// ---------------- persistent RNN v7 (round-14 verified best): 8 waves, NT stores ----------------
__global__ __launch_bounds__(512, 2) void rnn_all_kernel(
    f16* __restrict__ hs_hi, const f16* __restrict__ Wh_t,
    const float* __restrict__ xw, const float* __restrict__ bh)
{
  __shared__ __align__(16) char Hs[2][2][16384];   // [buf][plane(hi,lo)]
  const int tid = threadIdx.x, lane = tid & 63, w = tid >> 6;   // 8 waves
  const int n0 = blockIdx.x * 16;
  const int q = lane >> 4, ln = lane & 15;
  const int cbase = w * 64;

  float xwbh[4][4];
  {
    const float* xwrow = xw + (size_t)(n0 + ln) * HID + cbase + (q << 2);
    const float* bhp   = bh + cbase + (q << 2);
#pragma unroll
    for (int nt = 0; nt < 4; ++nt) {
      float4 xv = *(const float4*)(xwrow + nt * 16);
      float4 bv = *(const float4*)(bhp + nt * 16);
      xwbh[nt][0] = xv.x + bv.x;
      xwbh[nt][1] = xv.y + bv.y;
      xwbh[nt][2] = xv.z + bv.z;
      xwbh[nt][3] = xv.w + bv.w;
    }
  }

  f16x8 wh01[2][16];
#pragma unroll
  for (int nt = 0; nt < 2; ++nt) {
    const char* pA = (const char*)Wh_t + ((size_t)(cbase + nt * 16 + ln) << 10) + (q << 4);
#pragma unroll
    for (int ks = 0; ks < 16; ++ks)
      wh01[nt][ks] = *(const f16x8*)(pA + (ks << 6));
  }
  const char* pA2 = (const char*)Wh_t + ((size_t)(cbase + 32 + ln) << 10) + (q << 4);
  const char* pA3 = (const char*)Wh_t + ((size_t)(cbase + 48 + ln) << 10) + (q << 4);

  int wo[4];
#pragma unroll
  for (int nt = 0; nt < 4; ++nt) {
    const int ksp  = w * 2 + (nt >> 1);
    const int kgrp = ((nt & 1) << 1) | (q >> 1);
    wo[nt] = (ksp << 10) | (kgrp << 8) | ((ln ^ (ksp & 7)) << 4) | ((q & 1) << 3);
  }

  const int cks = lane >> 2;
  const int src0 = (cks << 10) | ((lane & 3) << 8) | ((w ^ (cks & 7)) << 4);
  const int src1 = (cks << 10) | ((lane & 3) << 8) | (((w + 8) ^ (cks & 7)) << 4);
  char* gdst0 = (char*)hs_hi + (((size_t)(n0 + w) * LSEQ) << 10) + (lane << 4);
  char* gdst1 = (char*)hs_hi + (((size_t)(n0 + w + 8) * LSEQ) << 10) + (lane << 4);

  for (int ts = 0; ts < LSEQ; ++ts) {
    f32x4 acc[4] = {};
    if (ts > 0) {
      const char* Hb = Hs[(ts - 1) & 1][0];
      f16x8 c2 = *(const f16x8*)(pA2);
      f16x8 c3 = *(const f16x8*)(pA3);
#pragma unroll
      for (int ks = 0; ks < 16; ++ks) {
        f16x8 t2 = c2, t3 = c3;
        if (ks < 15) {
          c2 = *(const f16x8*)(pA2 + ((ks + 1) << 6));
          c3 = *(const f16x8*)(pA3 + ((ks + 1) << 6));
        }
        const int ro = (ks << 10) | ((lane ^ (ks & 7)) << 4);
        f16x8 bhf = *(const f16x8*)(Hb + ro);
        f16x8 blf = *(const f16x8*)(Hb + 16384 + ro);
        acc[0] = __builtin_amdgcn_mfma_f32_16x16x32_f16(wh01[0][ks], bhf, acc[0], 0, 0, 0);
        acc[1] = __builtin_amdgcn_mfma_f32_16x16x32_f16(wh01[1][ks], bhf, acc[1], 0, 0, 0);
        acc[2] = __builtin_amdgcn_mfma_f32_16x16x32_f16(t2, bhf, acc[2], 0, 0, 0);
        acc[3] = __builtin_amdgcn_mfma_f32_16x16x32_f16(t3, bhf, acc[3], 0, 0, 0);
        acc[0] = __builtin_amdgcn_mfma_f32_16x16x32_f16(wh01[0][ks], blf, acc[0], 0, 0, 0);
        acc[1] = __builtin_amdgcn_mfma_f32_16x16x32_f16(wh01[1][ks], blf, acc[1], 0, 0, 0);
        acc[2] = __builtin_amdgcn_mfma_f32_16x16x32_f16(t2, blf, acc[2], 0, 0, 0);
        acc[3] = __builtin_amdgcn_mfma_f32_16x16x32_f16(t3, blf, acc[3], 0, 0, 0);
      }
    }
    char* Hw = Hs[ts & 1][0];
#pragma unroll
    for (int nt = 0; nt < 4; ++nt) {
      union { u64 u; f16 h[4]; } H, L;
#pragma unroll
      for (int i = 0; i < 4; ++i) {
        float v = fast_tanh(acc[nt][i] + xwbh[nt][i]);
        f16 hi = (f16)v;
        H.h[i] = hi;
        L.h[i] = (f16)(v - (float)hi);
      }
      *(u64*)(Hw + wo[nt])         = H.u;
      *(u64*)(Hw + 16384 + wo[nt]) = L.u;
    }
    __syncthreads();
    __builtin_nontemporal_store(*(const i32x4*)(Hw + src0), (i32x4*)(gdst0 + (ts << 10)));
    __builtin_nontemporal_store(*(const i32x4*)(Hw + src1), (i32x4*)(gdst1 + (ts << 10)));
  }
}

// ---------------- fused Ted_Conv1d: round-4 structure, tap loop templated on G ----------------
template<int G>
__device__ __forceinline__ void conv_body(
    const f16* __restrict__ hs_hi, const f16* __restrict__ Wc_t,
    const float* __restrict__ bg, float pa, f16* __restrict__ y,
    int r0, int tid, char* At0, char* At1, char* Bt0, char* Bt1)
{
  constexpr int TAPS = 2 * G + 1;
  const int lane = tid & 63, wave = tid >> 6;
  const int wr = (wave >> 1) * 64, wc = (wave & 1) * 64;
  const int q = lane >> 4, ln = lane & 15, qb = q << 4;

  const int srow = tid >> 1;
  const int sb   = (tid & 1) << 5;
  const char* srcA  = (const char*)(hs_hi + (size_t)(r0 + srow) * HID) + sb;
  const char* srcB0 = (const char*)(Wc_t + ((size_t)(3 - G) * HID + (G * 128 + srow)) * HID) + sb;
  const int wA0 = offA(srow, sb), wA1 = offA(srow, sb + 16);

  int aOff[TAPS][4], bOff[4];
#pragma unroll
  for (int tp = 0; tp < TAPS; ++tp) {
    const int dl = tp - G;
#pragma unroll
    for (int m = 0; m < 4; ++m) {
      const int lr = wr + m * 16 + ln;
      int tt = (lr & 31) + dl;
      tt = (tt < 0) ? -tt : ((tt > 31) ? 62 - tt : tt);   // reflect
      aOff[tp][m] = offA((lr & ~31) | tt, qb);
    }
  }
#pragma unroll
  for (int n = 0; n < 4; ++n) bOff[n] = offA(wc + n * 16 + ln, qb);

  *(int4*)(At0 + wA0) = *(const int4*)(srcA);
  *(int4*)(At0 + wA1) = *(const int4*)(srcA + 16);
  *(int4*)(Bt0 + wA0) = *(const int4*)(srcB0);
  *(int4*)(Bt0 + wA1) = *(const int4*)(srcB0 + 16);
  __syncthreads();

  f32x4 acc[4][4] = {};
  char* Ac = At0; char* An = At1; char* Bc = Bt0; char* Bn = Bt1;

  for (int kk = 0; kk < 16; ++kk) {
#pragma unroll
    for (int tp = 0; tp < TAPS; ++tp) {
      const bool tpLast = (tp == TAPS - 1);
      const bool lastPhase = tpLast && (kk == 15);
      const int nkk = tpLast ? kk + 1 : kk;
      const int ntp = tpLast ? 0 : tp + 1;
      int4 rb0, rb1, ra0, ra1;
      if (!lastPhase) {
        const char* p = srcB0 + (size_t)ntp * (512 * 512 * 2) + nkk * 64;
        rb0 = *(const int4*)(p);
        rb1 = *(const int4*)(p + 16);
        if (tpLast) {
          ra0 = *(const int4*)(srcA + nkk * 64);
          ra1 = *(const int4*)(srcA + nkk * 64 + 16);
        }
      }
      f16x8 af[4], bf[4];
#pragma unroll
      for (int m = 0; m < 4; ++m)
        af[m] = *(const f16x8*)(Ac + aOff[tp][m]);
#pragma unroll
      for (int n = 0; n < 4; ++n)
        bf[n] = *(const f16x8*)(Bc + bOff[n]);
      __builtin_amdgcn_s_setprio(1);
#pragma unroll
      for (int m = 0; m < 4; ++m)
#pragma unroll
        for (int n = 0; n < 4; ++n)
          acc[m][n] = __builtin_amdgcn_mfma_f32_16x16x32_f16(af[m], bf[n], acc[m][n], 0, 0, 0);
      __builtin_amdgcn_s_setprio(0);
      if (!lastPhase) {
        *(int4*)(Bn + wA0) = rb0;
        *(int4*)(Bn + wA1) = rb1;
        if (tpLast) {
          *(int4*)(An + wA0) = ra0;
          *(int4*)(An + wA1) = ra1;
        }
        __syncthreads();
        { char* t = Bc; Bc = Bn; Bn = t; }
        if (tpLast) { char* t = Ac; Ac = An; An = t; }
      }
    }
  }

#pragma unroll
  for (int m = 0; m < 4; ++m)
#pragma unroll
    for (int i = 0; i < 4; ++i) {
      const int R = r0 + wr + m * 16 + q * 4 + i;
#pragma unroll
      for (int n = 0; n < 4; ++n) {
        const int cg = wc + n * 16 + ln;
        float v = acc[m][n][i] + bg[cg];
        v = (v >= 0.f) ? v : pa * v;
        y[(size_t)R * HID + G * 128 + cg] = (f16)v;
      }
    }
}

__global__ __launch_bounds__(256) void conv_mfma_kernel(
    const f16* __restrict__ hs_hi, const f16* __restrict__ Wc_t,
    const float* __restrict__ b1, const float* __restrict__ b3,
    const float* __restrict__ b5, const float* __restrict__ b7,
    const float* __restrict__ prelu_a, f16* __restrict__ y)
{
  __shared__ __align__(16) char At0[8192], At1[8192], Bt0[8192], Bt1[8192];
  const int g = blockIdx.y, r0 = blockIdx.x * 128;
  const int tid = threadIdx.x;
  const float pa = *prelu_a;
  switch (g) {
    case 0: conv_body<0>(hs_hi, Wc_t, b1, pa, y, r0, tid, At0, At1, Bt0, Bt1); break;
    case 1: conv_body<1>(hs_hi, Wc_t, b3, pa, y, r0, tid, At0, At1, Bt0, Bt1); break;
    case 2: conv_body<2>(hs_hi, Wc_t, b5, pa, y, r0, tid, At0, At1, Bt0, Bt1); break;
    default: conv_body<3>(hs_hi, Wc_t, b7, pa, y, r0, tid, At0, At1, Bt0, Bt1); break;
  }
}

// ---------------- out GEMM: y streamed direct-from-global (no A LDS, no in-loop barriers) ----------------
__global__ __launch_bounds__(256) void out_mfma_kernel(
    const f16* __restrict__ y, const f16* __restrict__ Wout_t,
    const float* __restrict__ bout, float* __restrict__ out)
{
  __shared__ __align__(16) char Bl[65536];        // 64 x 1KB (Wout_t, all K)
  const int tid = threadIdx.x, lane = tid & 63, wave = tid >> 6;
  const int r0 = blockIdx.x * 128;
  const int q = lane >> 4, ln = lane & 15;

  {
    const int rr = tid >> 2;
    const char* src = (const char*)(Wout_t + (size_t)rr * HID);
#pragma unroll
    for (int i = 0; i < 16; ++i) {
      const int cb = (((tid & 3) + (i << 2)) << 4);
      *(int4*)(Bl + offB(rr, cb)) = *(const int4*)(src + cb);
    }
  }
  __syncthreads();

  // A fragments read directly from global y (stream-once data, no reuse)
  const char* pA0 = (const char*)(y + (size_t)(r0 + wave * 32 + ln) * HID) + (q << 4);
  const char* pA1 = pA0 + 16 * 1024;   // +16 rows (1KB/row)

  f32x4 acc[2][4] = {};
#pragma unroll
  for (int ks = 0; ks < 16; ++ks) {
    f16x8 a0 = *(const f16x8*)(pA0 + (ks << 6));
    f16x8 a1 = *(const f16x8*)(pA1 + (ks << 6));
    f16x8 bf[4];
#pragma unroll
    for (int n = 0; n < 4; ++n)
      bf[n] = *(const f16x8*)(Bl + offB(n * 16 + ln, (ks << 6) + (q << 4)));
#pragma unroll
    for (int n = 0; n < 4; ++n) {
      acc[0][n] = __builtin_amdgcn_mfma_f32_16x16x32_f16(a0, bf[n], acc[0][n], 0, 0, 0);
      acc[1][n] = __builtin_amdgcn_mfma_f32_16x16x32_f16(a1, bf[n], acc[1][n], 0, 0, 0);
    }
  }
#pragma unroll
  for (int m = 0; m < 2; ++m)
#pragma unroll
    for (int i = 0; i < 4; ++i) {
      const int R = r0 + wave * 32 + m * 16 + q * 4 + i;
#pragma unroll
      for (int n = 0; n < 4; ++n) {
        const int C = n * 16 + ln;
        out[(size_t)R * CCH + C] = acc[m][n][i] + bout[C];
      }
    }
}

// ---------------- end-token mask, in place on d_out ----------------
__global__ void mask_kernel(float* __restrict__ out) {
  const int row  = blockIdx.x;
  const int lane = threadIdx.x;
  float* base = out + (long)row * (LSEQ * CCH);
  int ended = 0;
  for (int l = 0; l < LSEQ; ++l) {
    float v = base[l * CCH + lane];
    float mv = v; int mi = lane;
#pragma unroll
    for (int off = 32; off > 0; off >>= 1) {
      float ov = __shfl_xor(mv, off);
      int   oi = __shfl_xor(mi, off);
      if (ov > mv || (ov == mv && oi < mi)) { mv = ov; mi = oi; }
    }
    if (ended) base[l * CCH + lane] = 0.f;
    ended |= (mi == 0);
  }
}

extern "C" void kernel_launch(void* const* d_in, const int* in_sizes, int n_in,
                              void* d_out, int out_size, void* d_ws, size_t ws_size,
                              hipStream_t stream) {
  const float* x    = (const float*)d_in[0];
  const float* Wx   = (const float*)d_in[1];
  const float* bx   = (const float*)d_in[2];
  const float* Wh   = (const float*)d_in[3];
  const float* bh   = (const float*)d_in[4];
  const float* pa   = (const float*)d_in[5];
  const float* Wout = (const float*)d_in[6];
  const float* bout = (const float*)d_in[7];
  const float* cw1  = (const float*)d_in[8];
  const float* cb1  = (const float*)d_in[9];
  const float* cw3  = (const float*)d_in[10];
  const float* cb3  = (const float*)d_in[11];
  const float* cw5  = (const float*)d_in[12];
  const float* cb5  = (const float*)d_in[13];
  const float* cw7  = (const float*)d_in[14];
  const float* cb7  = (const float*)d_in[15];
  float* out = (float*)d_out;

  // workspace layout with lifetime aliasing (~120 MiB <= proven ws floor 143.6 MiB)
  char* ws = (char*)d_ws;
  f16*   hs_hi  = (f16*)(ws);                       // 64 MiB   [rnn .. conv]
  f16*   Wout_t = (f16*)(ws + 67108864);            // 64 KiB   [pack .. out]
  f16*   Wc_t   = (f16*)(ws + 67174400);            // 3.5 MiB  [pack .. conv]
  char*  big    = ws + 70844416;                    // 64 MiB union region
  float* xw     = (float*)(big);                    // 4 MiB    [xw .. rnn end]
  f16*   Wh_t   = (f16*)(big + 4194304);            // 0.5 MiB  [pack .. rnn end]
  f16*   Wx_t   = (f16*)(big + 4718592);            // 1.5 MiB  [pack .. xw]
  f16*   y      = (f16*)(big);                      // 64 MiB   [conv .. out] (aliases the above)

  pack_wc_kernel<<<7 * 512 * 512 / 256, 256, 0, stream>>>(cw1, cw3, cw5, cw7, Wc_t);
  pack_misc_kernel<<<4224, 256, 0, stream>>>(Wh, Wout, Wx, Wh_t, Wout_t, Wx_t);

  // xw = x @ Wx + bx (x converted to f16 hi/lo on the fly in staging)
  xw_mfma_kernel<<<dim3(NROW / 64, HID / 128), 256, 0, stream>>>(x, Wx_t, bx, xw);

  // all 32 steps in ONE kernel (round-14 verified v7)
  rnn_all_kernel<<<NROW / 16, 512, 0, stream>>>(hs_hi, Wh_t, xw, bh);

  // conv: round-4 structure, tap loop templated/unrolled per G
  conv_mfma_kernel<<<dim3(NL / 128, 4), 256, 0, stream>>>(
      hs_hi, Wc_t, cb1, cb3, cb5, cb7, pa, y);

  // out GEMM: A direct-from-global, zero in-loop barriers
  out_mfma_kernel<<<NL / 128, 256, 0, stream>>>(y, Wout_t, bout, out);

  mask_kernel<<<NROW, 64, 0, stream>>>(out);
}

// Round 22
// 411.253 us; speedup vs baseline: 1.0157x; 1.0157x over previous
//
#include <hip/hip_runtime.h>
#include <cmath>

#define LSEQ 32
#define HID  512
#define DIN  1536
#define CCH  64
#define NROW 2048          // E*S
#define NL   65536         // NROW*LSEQ

typedef _Float16 f16;
typedef _Float16 f16x8 __attribute__((ext_vector_type(8)));
typedef float    f32x4 __attribute__((ext_vector_type(4)));
typedef int      i32x4 __attribute__((ext_vector_type(4)));
typedef unsigned long long u64;

__device__ __forceinline__ float fast_tanh(float x) {
  float e = __expf(2.0f * x);
  return 1.0f - 2.0f * __builtin_amdgcn_rcpf(e + 1.0f);
}

// 64B-row LDS tile, 16B-granularity XOR swizzle
__device__ __forceinline__ int offA(int r, int b) {
  return (r << 6) + (b ^ (((r >> 1) & 3) << 4));
}
// 1KB-row LDS tile
__device__ __forceinline__ int offB(int r, int b) {
  return (r << 10) + (b ^ ((r & 7) << 4));
}

// ---------------- pack conv weights transposed: Wc_t[dl+3][c][k] f16 ----------------
__global__ void pack_wc_kernel(const float* __restrict__ w1, const float* __restrict__ w3,
                               const float* __restrict__ w5, const float* __restrict__ w7,
                               f16* __restrict__ Wc_t) {
  int idx = blockIdx.x * 256 + threadIdx.x;
  if (idx >= 7 * 512 * 512) return;
  int k   = idx & 511;
  int c   = (idx >> 9) & 511;
  int dli = idx >> 18;
  int dl  = dli - 3;
  int g   = c >> 7, cg = c & 127;
  int K   = 2 * g + 1;
  int kk  = dl + g;
  float v = 0.f;
  if (kk >= 0 && kk < K) {
    const float* w = (g == 0) ? w1 : (g == 1) ? w3 : (g == 2) ? w5 : w7;
    v = w[(cg * 512 + k) * K + kk];
  }
  Wc_t[idx] = (f16)v;
}

// ---------------- pack Wh^T, Wout^T, Wx^T as f16 ----------------
__global__ void pack_misc_kernel(const float* __restrict__ Wh, const float* __restrict__ Wout,
                                 const float* __restrict__ Wx,
                                 f16* __restrict__ Wh_t, f16* __restrict__ Wout_t,
                                 f16* __restrict__ Wx_t) {
  int idx = blockIdx.x * 256 + threadIdx.x;
  if (idx < 512 * 512) {
    int n = idx >> 9, k = idx & 511;
    Wh_t[idx] = (f16)Wh[k * 512 + n];
  } else if (idx < 512 * 512 + 64 * 512) {
    int j = idx - 512 * 512;
    int c = j >> 9, k = j & 511;
    Wout_t[j] = (f16)Wout[k * 64 + c];
  } else {
    int j = idx - (512 * 512 + 64 * 512);
    if (j < 512 * 1536) {
      int n = j / 1536, k = j - n * 1536;
      Wx_t[j] = (f16)Wx[k * 512 + n];
    }
  }
}

// ---------------- xw = x @ Wx + bx via f16 MFMA; x converted to hi/lo ON THE FLY ----------------
__global__ __launch_bounds__(256) void xw_mfma_kernel(
    const float* __restrict__ x, const f16* __restrict__ Wx_t,
    const float* __restrict__ bx, float* __restrict__ xw)
{
  __shared__ __align__(16) char Ah[2][4096], Al[2][4096], Bt[2][8192];
  const int tid = threadIdx.x, lane = tid & 63, wave = tid >> 6;
  const int r0 = blockIdx.x * 64, c0 = blockIdx.y * 128;
  const int wr = (wave >> 1) * 32, wc = (wave & 1) * 64;
  const int q = lane >> 4, ln = lane & 15, qb = q << 4;

  const int arow = tid & 63, acb = (tid >> 6) << 4;   // 16B f16 chunk per thread
  const char* srcX = (const char*)(x + (size_t)(r0 + arow) * DIN) + (acb << 1);  // 32B f32
  const int wAo = offA(arow, acb);
  const int brow = tid & 127, bcb = (tid >> 7) << 5;
  const char* srcB = (const char*)(Wx_t + (size_t)(c0 + brow) * DIN) + bcb;
  const int wB0 = offA(brow, bcb), wB1 = offA(brow, bcb + 16);

  {
    float4 xa = *(const float4*)(srcX);
    float4 xb = *(const float4*)(srcX + 16);
    const float f[8] = {xa.x, xa.y, xa.z, xa.w, xb.x, xb.y, xb.z, xb.w};
    union { int4 i; f16 h[8]; } Hi, Lo;
#pragma unroll
    for (int j = 0; j < 8; ++j) {
      f16 hi = (f16)f[j];
      Hi.h[j] = hi;
      Lo.h[j] = (f16)(f[j] - (float)hi);
    }
    *(int4*)(Ah[0] + wAo) = Hi.i;
    *(int4*)(Al[0] + wAo) = Lo.i;
  }
  *(int4*)(Bt[0] + wB0) = *(const int4*)(srcB);
  *(int4*)(Bt[0] + wB1) = *(const int4*)(srcB + 16);
  __syncthreads();

  f32x4 acc[2][4] = {};
  for (int kk = 0; kk < 48; ++kk) {
    const int buf = kk & 1;
    float4 xa, xb;
    int4 rb0, rb1;
    if (kk < 47) {
      xa  = *(const float4*)(srcX + (kk + 1) * 128);
      xb  = *(const float4*)(srcX + (kk + 1) * 128 + 16);
      rb0 = *(const int4*)(srcB + (kk + 1) * 64);
      rb1 = *(const int4*)(srcB + (kk + 1) * 64 + 16);
    }
    f16x8 bf[4];
#pragma unroll
    for (int n = 0; n < 4; ++n)
      bf[n] = *(const f16x8*)(Bt[buf] + offA(wc + n * 16 + ln, qb));
#pragma unroll
    for (int m = 0; m < 2; ++m) {
      f16x8 ah = *(const f16x8*)(Ah[buf] + offA(wr + m * 16 + ln, qb));
      f16x8 al = *(const f16x8*)(Al[buf] + offA(wr + m * 16 + ln, qb));
#pragma unroll
      for (int n = 0; n < 4; ++n) {
        acc[m][n] = __builtin_amdgcn_mfma_f32_16x16x32_f16(ah, bf[n], acc[m][n], 0, 0, 0);
        acc[m][n] = __builtin_amdgcn_mfma_f32_16x16x32_f16(al, bf[n], acc[m][n], 0, 0, 0);
      }
    }
    if (kk < 47) {
      const float f[8] = {xa.x, xa.y, xa.z, xa.w, xb.x, xb.y, xb.z, xb.w};
      union { int4 i; f16 h[8]; } Hi, Lo;
#pragma unroll
      for (int j = 0; j < 8; ++j) {
        f16 hi = (f16)f[j];
        Hi.h[j] = hi;
        Lo.h[j] = (f16)(f[j] - (float)hi);
      }
      *(int4*)(Ah[buf ^ 1] + wAo) = Hi.i;
      *(int4*)(Al[buf ^ 1] + wAo) = Lo.i;
      *(int4*)(Bt[buf ^ 1] + wB0) = rb0;
      *(int4*)(Bt[buf ^ 1] + wB1) = rb1;
      __syncthreads();
    }
  }
#pragma unroll
  for (int m = 0; m < 2; ++m)
#pragma unroll
    for (int i = 0; i < 4; ++i) {
      const int R = r0 + wr + m * 16 + q * 4 + i;
#pragma unroll
      for (int n = 0; n < 4; ++n) {
        const int C = c0 + wc + n * 16 + ln;
        xw[(size_t)R * HID + C] = acc[m][n][i] + bx[C];
      }
    }
}

// ---------------- persistent RNN v7 (round-14 verified best): 8 waves, NT stores ----------------
__global__ __launch_bounds__(512, 2) void rnn_all_kernel(
    f16* __restrict__ hs_hi, const f16* __restrict__ Wh_t,
    const float* __restrict__ xw, const float* __restrict__ bh)
{
  __shared__ __align__(16) char Hs[2][2][16384];   // [buf][plane(hi,lo)]
  const int tid = threadIdx.x, lane = tid & 63, w = tid >> 6;   // 8 waves
  const int n0 = blockIdx.x * 16;
  const int q = lane >> 4, ln = lane & 15;
  const int cbase = w * 64;

  float xwbh[4][4];
  {
    const float* xwrow = xw + (size_t)(n0 + ln) * HID + cbase + (q << 2);
    const float* bhp   = bh + cbase + (q << 2);
#pragma unroll
    for (int nt = 0; nt < 4; ++nt) {
      float4 xv = *(const float4*)(xwrow + nt * 16);
      float4 bv = *(const float4*)(bhp + nt * 16);
      xwbh[nt][0] = xv.x + bv.x;
      xwbh[nt][1] = xv.y + bv.y;
      xwbh[nt][2] = xv.z + bv.z;
      xwbh[nt][3] = xv.w + bv.w;
    }
  }

  f16x8 wh01[2][16];
#pragma unroll
  for (int nt = 0; nt < 2; ++nt) {
    const char* pA = (const char*)Wh_t + ((size_t)(cbase + nt * 16 + ln) << 10) + (q << 4);
#pragma unroll
    for (int ks = 0; ks < 16; ++ks)
      wh01[nt][ks] = *(const f16x8*)(pA + (ks << 6));
  }
  const char* pA2 = (const char*)Wh_t + ((size_t)(cbase + 32 + ln) << 10) + (q << 4);
  const char* pA3 = (const char*)Wh_t + ((size_t)(cbase + 48 + ln) << 10) + (q << 4);

  int wo[4];
#pragma unroll
  for (int nt = 0; nt < 4; ++nt) {
    const int ksp  = w * 2 + (nt >> 1);
    const int kgrp = ((nt & 1) << 1) | (q >> 1);
    wo[nt] = (ksp << 10) | (kgrp << 8) | ((ln ^ (ksp & 7)) << 4) | ((q & 1) << 3);
  }

  const int cks = lane >> 2;
  const int src0 = (cks << 10) | ((lane & 3) << 8) | ((w ^ (cks & 7)) << 4);
  const int src1 = (cks << 10) | ((lane & 3) << 8) | (((w + 8) ^ (cks & 7)) << 4);
  char* gdst0 = (char*)hs_hi + (((size_t)(n0 + w) * LSEQ) << 10) + (lane << 4);
  char* gdst1 = (char*)hs_hi + (((size_t)(n0 + w + 8) * LSEQ) << 10) + (lane << 4);

  for (int ts = 0; ts < LSEQ; ++ts) {
    f32x4 acc[4] = {};
    if (ts > 0) {
      const char* Hb = Hs[(ts - 1) & 1][0];
      f16x8 c2 = *(const f16x8*)(pA2);
      f16x8 c3 = *(const f16x8*)(pA3);
#pragma unroll
      for (int ks = 0; ks < 16; ++ks) {
        f16x8 t2 = c2, t3 = c3;
        if (ks < 15) {
          c2 = *(const f16x8*)(pA2 + ((ks + 1) << 6));
          c3 = *(const f16x8*)(pA3 + ((ks + 1) << 6));
        }
        const int ro = (ks << 10) | ((lane ^ (ks & 7)) << 4);
        f16x8 bhf = *(const f16x8*)(Hb + ro);
        f16x8 blf = *(const f16x8*)(Hb + 16384 + ro);
        acc[0] = __builtin_amdgcn_mfma_f32_16x16x32_f16(wh01[0][ks], bhf, acc[0], 0, 0, 0);
        acc[1] = __builtin_amdgcn_mfma_f32_16x16x32_f16(wh01[1][ks], bhf, acc[1], 0, 0, 0);
        acc[2] = __builtin_amdgcn_mfma_f32_16x16x32_f16(t2, bhf, acc[2], 0, 0, 0);
        acc[3] = __builtin_amdgcn_mfma_f32_16x16x32_f16(t3, bhf, acc[3], 0, 0, 0);
        acc[0] = __builtin_amdgcn_mfma_f32_16x16x32_f16(wh01[0][ks], blf, acc[0], 0, 0, 0);
        acc[1] = __builtin_amdgcn_mfma_f32_16x16x32_f16(wh01[1][ks], blf, acc[1], 0, 0, 0);
        acc[2] = __builtin_amdgcn_mfma_f32_16x16x32_f16(t2, blf, acc[2], 0, 0, 0);
        acc[3] = __builtin_amdgcn_mfma_f32_16x16x32_f16(t3, blf, acc[3], 0, 0, 0);
      }
    }
    char* Hw = Hs[ts & 1][0];
#pragma unroll
    for (int nt = 0; nt < 4; ++nt) {
      union { u64 u; f16 h[4]; } H, L;
#pragma unroll
      for (int i = 0; i < 4; ++i) {
        float v = fast_tanh(acc[nt][i] + xwbh[nt][i]);
        f16 hi = (f16)v;
        H.h[i] = hi;
        L.h[i] = (f16)(v - (float)hi);
      }
      *(u64*)(Hw + wo[nt])         = H.u;
      *(u64*)(Hw + 16384 + wo[nt]) = L.u;
    }
    __syncthreads();
    __builtin_nontemporal_store(*(const i32x4*)(Hw + src0), (i32x4*)(gdst0 + (ts << 10)));
    __builtin_nontemporal_store(*(const i32x4*)(Hw + src1), (i32x4*)(gdst1 + (ts << 10)));
  }
}

// ---------------- fused Ted_Conv1d: round-4 structure, tap loop templated on G ----------------
template<int G>
__device__ __forceinline__ void conv_body(
    const f16* __restrict__ hs_hi, const f16* __restrict__ Wc_t,
    const float* __restrict__ bg, float pa, f16* __restrict__ y,
    int r0, int tid, char* At0, char* At1, char* Bt0, char* Bt1)
{
  constexpr int TAPS = 2 * G + 1;
  const int lane = tid & 63, wave = tid >> 6;
  const int wr = (wave >> 1) * 64, wc = (wave & 1) * 64;
  const int q = lane >> 4, ln = lane & 15, qb = q << 4;

  const int srow = tid >> 1;
  const int sb   = (tid & 1) << 5;
  const char* srcA  = (const char*)(hs_hi + (size_t)(r0 + srow) * HID) + sb;
  const char* srcB0 = (const char*)(Wc_t + ((size_t)(3 - G) * HID + (G * 128 + srow)) * HID) + sb;
  const int wA0 = offA(srow, sb), wA1 = offA(srow, sb + 16);

  int aOff[TAPS][4], bOff[4];
#pragma unroll
  for (int tp = 0; tp < TAPS; ++tp) {
    const int dl = tp - G;
#pragma unroll
    for (int m = 0; m < 4; ++m) {
      const int lr = wr + m * 16 + ln;
      int tt = (lr & 31) + dl;
      tt = (tt < 0) ? -tt : ((tt > 31) ? 62 - tt : tt);   // reflect
      aOff[tp][m] = offA((lr & ~31) | tt, qb);
    }
  }
#pragma unroll
  for (int n = 0; n < 4; ++n) bOff[n] = offA(wc + n * 16 + ln, qb);

  *(int4*)(At0 + wA0) = *(const int4*)(srcA);
  *(int4*)(At0 + wA1) = *(const int4*)(srcA + 16);
  *(int4*)(Bt0 + wA0) = *(const int4*)(srcB0);
  *(int4*)(Bt0 + wA1) = *(const int4*)(srcB0 + 16);
  __syncthreads();

  f32x4 acc[4][4] = {};
  char* Ac = At0; char* An = At1; char* Bc = Bt0; char* Bn = Bt1;

  for (int kk = 0; kk < 16; ++kk) {
#pragma unroll
    for (int tp = 0; tp < TAPS; ++tp) {
      const bool tpLast = (tp == TAPS - 1);
      const bool lastPhase = tpLast && (kk == 15);
      const int nkk = tpLast ? kk + 1 : kk;
      const int ntp = tpLast ? 0 : tp + 1;
      int4 rb0, rb1, ra0, ra1;
      if (!lastPhase) {
        const char* p = srcB0 + (size_t)ntp * (512 * 512 * 2) + nkk * 64;
        rb0 = *(const int4*)(p);
        rb1 = *(const int4*)(p + 16);
        if (tpLast) {
          ra0 = *(const int4*)(srcA + nkk * 64);
          ra1 = *(const int4*)(srcA + nkk * 64 + 16);
        }
      }
      f16x8 af[4], bf[4];
#pragma unroll
      for (int m = 0; m < 4; ++m)
        af[m] = *(const f16x8*)(Ac + aOff[tp][m]);
#pragma unroll
      for (int n = 0; n < 4; ++n)
        bf[n] = *(const f16x8*)(Bc + bOff[n]);
      __builtin_amdgcn_s_setprio(1);
#pragma unroll
      for (int m = 0; m < 4; ++m)
#pragma unroll
        for (int n = 0; n < 4; ++n)
          acc[m][n] = __builtin_amdgcn_mfma_f32_16x16x32_f16(af[m], bf[n], acc[m][n], 0, 0, 0);
      __builtin_amdgcn_s_setprio(0);
      if (!lastPhase) {
        *(int4*)(Bn + wA0) = rb0;
        *(int4*)(Bn + wA1) = rb1;
        if (tpLast) {
          *(int4*)(An + wA0) = ra0;
          *(int4*)(An + wA1) = ra1;
        }
        __syncthreads();
        { char* t = Bc; Bc = Bn; Bn = t; }
        if (tpLast) { char* t = Ac; Ac = An; An = t; }
      }
    }
  }

#pragma unroll
  for (int m = 0; m < 4; ++m)
#pragma unroll
    for (int i = 0; i < 4; ++i) {
      const int R = r0 + wr + m * 16 + q * 4 + i;
#pragma unroll
      for (int n = 0; n < 4; ++n) {
        const int cg = wc + n * 16 + ln;
        float v = acc[m][n][i] + bg[cg];
        v = (v >= 0.f) ? v : pa * v;
        y[(size_t)R * HID + G * 128 + cg] = (f16)v;
      }
    }
}

__global__ __launch_bounds__(256, 3) void conv_mfma_kernel(
    const f16* __restrict__ hs_hi, const f16* __restrict__ Wc_t,
    const float* __restrict__ b1, const float* __restrict__ b3,
    const float* __restrict__ b5, const float* __restrict__ b7,
    const float* __restrict__ prelu_a, f16* __restrict__ y)
{
  __shared__ __align__(16) char At0[8192], At1[8192], Bt0[8192], Bt1[8192];
  const int g = blockIdx.y, r0 = blockIdx.x * 128;
  const int tid = threadIdx.x;
  const float pa = *prelu_a;
  switch (g) {
    case 0: conv_body<0>(hs_hi, Wc_t, b1, pa, y, r0, tid, At0, At1, Bt0, Bt1); break;
    case 1: conv_body<1>(hs_hi, Wc_t, b3, pa, y, r0, tid, At0, At1, Bt0, Bt1); break;
    case 2: conv_body<2>(hs_hi, Wc_t, b5, pa, y, r0, tid, At0, At1, Bt0, Bt1); break;
    default: conv_body<3>(hs_hi, Wc_t, b7, pa, y, r0, tid, At0, At1, Bt0, Bt1); break;
  }
}

// ---------------- out GEMM: y streamed direct-from-global (no A LDS, no in-loop barriers) ----------------
__global__ __launch_bounds__(256, 2) void out_mfma_kernel(
    const f16* __restrict__ y, const f16* __restrict__ Wout_t,
    const float* __restrict__ bout, float* __restrict__ out)
{
  __shared__ __align__(16) char Bl[65536];        // 64 x 1KB (Wout_t, all K)
  const int tid = threadIdx.x, lane = tid & 63, wave = tid >> 6;
  const int r0 = blockIdx.x * 128;
  const int q = lane >> 4, ln = lane & 15;

  {
    const int rr = tid >> 2;
    const char* src = (const char*)(Wout_t + (size_t)rr * HID);
#pragma unroll
    for (int i = 0; i < 16; ++i) {
      const int cb = (((tid & 3) + (i << 2)) << 4);
      *(int4*)(Bl + offB(rr, cb)) = *(const int4*)(src + cb);
    }
  }
  __syncthreads();

  const char* pA0 = (const char*)(y + (size_t)(r0 + wave * 32 + ln) * HID) + (q << 4);
  const char* pA1 = pA0 + 16 * 1024;   // +16 rows (1KB/row)

  f32x4 acc[2][4] = {};
#pragma unroll
  for (int ks = 0; ks < 16; ++ks) {
    f16x8 a0 = *(const f16x8*)(pA0 + (ks << 6));
    f16x8 a1 = *(const f16x8*)(pA1 + (ks << 6));
    f16x8 bf[4];
#pragma unroll
    for (int n = 0; n < 4; ++n)
      bf[n] = *(const f16x8*)(Bl + offB(n * 16 + ln, (ks << 6) + (q << 4)));
#pragma unroll
    for (int n = 0; n < 4; ++n) {
      acc[0][n] = __builtin_amdgcn_mfma_f32_16x16x32_f16(a0, bf[n], acc[0][n], 0, 0, 0);
      acc[1][n] = __builtin_amdgcn_mfma_f32_16x16x32_f16(a1, bf[n], acc[1][n], 0, 0, 0);
    }
  }
#pragma unroll
  for (int m = 0; m < 2; ++m)
#pragma unroll
    for (int i = 0; i < 4; ++i) {
      const int R = r0 + wave * 32 + m * 16 + q * 4 + i;
#pragma unroll
      for (int n = 0; n < 4; ++n) {
        const int C = n * 16 + ln;
        out[(size_t)R * CCH + C] = acc[m][n][i] + bout[C];
      }
    }
}

// ---------------- end-token mask, in place on d_out ----------------
__global__ void mask_kernel(float* __restrict__ out) {
  const int row  = blockIdx.x;
  const int lane = threadIdx.x;
  float* base = out + (long)row * (LSEQ * CCH);
  int ended = 0;
  for (int l = 0; l < LSEQ; ++l) {
    float v = base[l * CCH + lane];
    float mv = v; int mi = lane;
#pragma unroll
    for (int off = 32; off > 0; off >>= 1) {
      float ov = __shfl_xor(mv, off);
      int   oi = __shfl_xor(mi, off);
      if (ov > mv || (ov == mv && oi < mi)) { mv = ov; mi = oi; }
    }
    if (ended) base[l * CCH + lane] = 0.f;
    ended |= (mi == 0);
  }
}

extern "C" void kernel_launch(void* const* d_in, const int* in_sizes, int n_in,
                              void* d_out, int out_size, void* d_ws, size_t ws_size,
                              hipStream_t stream) {
  const float* x    = (const float*)d_in[0];
  const float* Wx   = (const float*)d_in[1];
  const float* bx   = (const float*)d_in[2];
  const float* Wh   = (const float*)d_in[3];
  const float* bh   = (const float*)d_in[4];
  const float* pa   = (const float*)d_in[5];
  const float* Wout = (const float*)d_in[6];
  const float* bout = (const float*)d_in[7];
  const float* cw1  = (const float*)d_in[8];
  const float* cb1  = (const float*)d_in[9];
  const float* cw3  = (const float*)d_in[10];
  const float* cb3  = (const float*)d_in[11];
  const float* cw5  = (const float*)d_in[12];
  const float* cb5  = (const float*)d_in[13];
  const float* cw7  = (const float*)d_in[14];
  const float* cb7  = (const float*)d_in[15];
  float* out = (float*)d_out;

  // workspace layout with lifetime aliasing (~120 MiB <= proven ws floor 143.6 MiB)
  char* ws = (char*)d_ws;
  f16*   hs_hi  = (f16*)(ws);                       // 64 MiB   [rnn .. conv]
  f16*   Wout_t = (f16*)(ws + 67108864);            // 64 KiB   [pack .. out]
  f16*   Wc_t   = (f16*)(ws + 67174400);            // 3.5 MiB  [pack .. conv]
  char*  big    = ws + 70844416;                    // 64 MiB union region
  float* xw     = (float*)(big);                    // 4 MiB    [xw .. rnn end]
  f16*   Wh_t   = (f16*)(big + 4194304);            // 0.5 MiB  [pack .. rnn end]
  f16*   Wx_t   = (f16*)(big + 4718592);            // 1.5 MiB  [pack .. xw]
  f16*   y      = (f16*)(big);                      // 64 MiB   [conv .. out] (aliases the above)

  pack_wc_kernel<<<7 * 512 * 512 / 256, 256, 0, stream>>>(cw1, cw3, cw5, cw7, Wc_t);
  pack_misc_kernel<<<4224, 256, 0, stream>>>(Wh, Wout, Wx, Wh_t, Wout_t, Wx_t);

  // xw = x @ Wx + bx (x converted to f16 hi/lo on the fly in staging)
  xw_mfma_kernel<<<dim3(NROW / 64, HID / 128), 256, 0, stream>>>(x, Wx_t, bx, xw);

  // all 32 steps in ONE kernel (round-14 verified v7)
  rnn_all_kernel<<<NROW / 16, 512, 0, stream>>>(hs_hi, Wh_t, xw, bh);

  // conv: templated taps + 3 blocks/CU occupancy request
  conv_mfma_kernel<<<dim3(NL / 128, 4), 256, 0, stream>>>(
      hs_hi, Wc_t, cb1, cb3, cb5, cb7, pa, y);

  // out GEMM: A direct-from-global, zero in-loop barriers
  out_mfma_kernel<<<NL / 128, 256, 0, stream>>>(y, Wout_t, bout, out);

  mask_kernel<<<NROW, 64, 0, stream>>>(out);
}